// Round 2
// baseline (1658.549 us; speedup 1.0000x reference)
//
#include <hip/hip_runtime.h>
#include <hip/hip_fp16.h>

#define NN 200000
#define EE 3200000
#define HID 32
#define NB 1563           // dst buckets of 128 nodes: 1563*128 = 200064 >= NN

// ---------------- fp16 pack helpers (4 halfs <-> float4, 8B memory op) ------

__device__ inline float4 ld_h4(const __half* p) {
    uint2 u = *reinterpret_cast<const uint2*>(p);
    __half2 a = *reinterpret_cast<__half2*>(&u.x);
    __half2 b = *reinterpret_cast<__half2*>(&u.y);
    float2 fa = __half22float2(a), fb = __half22float2(b);
    return make_float4(fa.x, fa.y, fb.x, fb.y);
}

__device__ inline void st_h4(__half* p, float4 v) {
    __half2 a = __floats2half2_rn(v.x, v.y);
    __half2 b = __floats2half2_rn(v.z, v.w);
    uint2 u;
    u.x = *reinterpret_cast<unsigned*>(&a);
    u.y = *reinterpret_cast<unsigned*>(&b);
    *reinterpret_cast<uint2*>(p) = u;
}

// ---------------- zero helper ----------------------------------------------

__global__ __launch_bounds__(256) void k_zero(int* __restrict__ p, int n) {
    int i = blockIdx.x * 256 + threadIdx.x;
    if (i < n) p[i] = 0;
}

// ---------------- src degrees (device atomics) + dst bucket hist (LDS) ------
// grid = 400 blocks; each thread grid-strides over int4 elements.

__global__ __launch_bounds__(256) void k_degb(const int* __restrict__ ei,
                                              int* __restrict__ dsrc,
                                              int* __restrict__ bcnt) {
    __shared__ int h[NB];
    for (int i = threadIdx.x; i < NB; i += 256) h[i] = 0;
    __syncthreads();
    const int4* s4 = reinterpret_cast<const int4*>(ei);
    const int4* d4 = reinterpret_cast<const int4*>(ei + EE);
    int stride = gridDim.x * 256;
    for (int t = blockIdx.x * 256 + threadIdx.x; t < EE / 4; t += stride) {
        int4 s = s4[t];
        atomicAdd(&dsrc[s.x], 1); atomicAdd(&dsrc[s.y], 1);
        atomicAdd(&dsrc[s.z], 1); atomicAdd(&dsrc[s.w], 1);
        int4 d = d4[t];
        atomicAdd(&h[d.x >> 7], 1); atomicAdd(&h[d.y >> 7], 1);
        atomicAdd(&h[d.z >> 7], 1); atomicAdd(&h[d.w >> 7], 1);
    }
    __syncthreads();
    for (int i = threadIdx.x; i < NB; i += 256)
        if (h[i]) atomicAdd(&bcnt[i], h[i]);
}

__global__ void k_dinv(const int* __restrict__ dsrc, float* __restrict__ dinv) {
    int i = blockIdx.x * 256 + threadIdx.x;
    if (i < NN) {
        int d = dsrc[i];
        dinv[i] = d > 0 ? rsqrtf((float)d) : 0.f;
    }
}

// ---------------- exclusive scan of bucket counts (single block) ------------

__global__ void k_bscan(const int* __restrict__ bcnt, int* __restrict__ bstart,
                        int* __restrict__ cursor) {
    __shared__ int s[256];
    __shared__ int carry;
    if (threadIdx.x == 0) carry = 0;
    __syncthreads();
    for (int base = 0; base < NB; base += 256) {
        int k = base + threadIdx.x;
        int v = (k < NB) ? bcnt[k] : 0;
        s[threadIdx.x] = v;
        __syncthreads();
        for (int off = 1; off < 256; off <<= 1) {
            int t = (threadIdx.x >= off) ? s[threadIdx.x - off] : 0;
            __syncthreads();
            s[threadIdx.x] += t;
            __syncthreads();
        }
        int excl = s[threadIdx.x] - v + carry;
        if (k < NB) { bstart[k] = excl; cursor[k] = excl; }
        __syncthreads();
        if (threadIdx.x == 0) carry += s[255];
        __syncthreads();
    }
    if (threadIdx.x == 0) bstart[NB] = EE;
}

// ---------------- stage A: scatter into coarse buckets ----------------------
// Write frontier = NB lines (~100KB) -> L2-resident, stores are L2 hits.
// Entry = (src << 7) | (dst & 127), 4B. grid = EE/1024 = 3125.

__global__ __launch_bounds__(256) void k_scatb(const int* __restrict__ ei,
                                               int* __restrict__ cursor,
                                               int* __restrict__ ebkt) {
    int t = blockIdx.x * 256 + threadIdx.x;
    const int4* s4 = reinterpret_cast<const int4*>(ei);
    const int4* d4 = reinterpret_cast<const int4*>(ei + EE);
    int4 s = s4[t];
    int4 d = d4[t];
    int p0 = atomicAdd(&cursor[d.x >> 7], 1);
    int p1 = atomicAdd(&cursor[d.y >> 7], 1);
    int p2 = atomicAdd(&cursor[d.z >> 7], 1);
    int p3 = atomicAdd(&cursor[d.w >> 7], 1);
    ebkt[p0] = (s.x << 7) | (d.x & 127);
    ebkt[p1] = (s.y << 7) | (d.y & 127);
    ebkt[p2] = (s.z << 7) | (d.z & 127);
    ebkt[p3] = (s.w << 7) | (d.w & 127);
}

// ---------------- stage B: bucket -> exact-dst CSR + rowptr -----------------
// One block per bucket; reads/writes are bucket-contiguous (~8KB/16KB).

__global__ __launch_bounds__(256) void k_fillb(const int* __restrict__ bstart,
                                               const int* __restrict__ ebkt,
                                               const float* __restrict__ dinv,
                                               int* __restrict__ rowptr,
                                               int2* __restrict__ csr) {
    __shared__ int deg[128], rank[128], excl[128];
    __shared__ float sdv[128];
    int b = blockIdx.x, tid = threadIdx.x;
    int beg = bstart[b], end = bstart[b + 1];
    int nbase = b << 7;
    if (tid < 128) {
        deg[tid] = 0; rank[tid] = 0;
        int node = nbase + tid;
        sdv[tid] = (node < NN) ? dinv[node] : 0.f;
    }
    __syncthreads();
    for (int j = beg + tid; j < end; j += 256)
        atomicAdd(&deg[ebkt[j] & 127], 1);
    __syncthreads();
    if (tid == 0) {
        int run = 0;
#pragma unroll
        for (int k = 0; k < 128; k++) { excl[k] = run; run += deg[k]; }
    }
    __syncthreads();
    if (tid < 128) {
        int node = nbase + tid;
        if (node < NN) rowptr[node] = beg + excl[tid];
    }
    if (b == 0 && tid == 0) rowptr[NN] = EE;
    for (int j = beg + tid; j < end; j += 256) {
        int e = ebkt[j];
        int l = e & 127, src = e >> 7;
        int r = atomicAdd(&rank[l], 1);
        float w = -dinv[src] * sdv[l];
        csr[beg + excl[l] + r] = make_int2(src, __float_as_int(w));
    }
}

// ---------------- input MLP: h = relu(x @ W0 + b0), fp16 out ----------------

__global__ void k_mlp0(const float* __restrict__ x, const float* __restrict__ W0,
                       const float* __restrict__ b0, __half* __restrict__ out) {
    int t = blockIdx.x * 256 + threadIdx.x;   // t = n*32 + o
    int n = t >> 5, o = t & 31;
    if (n < NN) {
        float acc = b0[o];
#pragma unroll
        for (int i = 0; i < 3; i++) acc += x[n * 3 + i] * W0[i * 32 + o];
        out[t] = __float2half(fmaxf(acc, 0.f));
    }
}

// ---------------- propagation (CSR, gather-only, fp16 features) -------------
// 8 threads/node, 4 halfs (8B) per thread => 1 cache line per edge row.

__global__ __launch_bounds__(256) void k_prop_csr(const int* __restrict__ rowptr,
                                                  const int2* __restrict__ csr,
                                                  const __half* __restrict__ x,
                                                  __half* __restrict__ y) {
    int t = blockIdx.x * 256 + threadIdx.x;
    int n = t >> 3, c = t & 7;
    if (n >= NN) return;
    int beg = rowptr[n], end = rowptr[n + 1];
    float4 acc = make_float4(0.f, 0.f, 0.f, 0.f);
    int j = beg;
    const __half* xc = x + (size_t)c * 4;
    for (; j + 8 <= end; j += 8) {
        int2 e0 = csr[j + 0], e1 = csr[j + 1], e2 = csr[j + 2], e3 = csr[j + 3];
        int2 e4 = csr[j + 4], e5 = csr[j + 5], e6 = csr[j + 6], e7 = csr[j + 7];
        float4 v0 = ld_h4(xc + (size_t)e0.x * 32);
        float4 v1 = ld_h4(xc + (size_t)e1.x * 32);
        float4 v2 = ld_h4(xc + (size_t)e2.x * 32);
        float4 v3 = ld_h4(xc + (size_t)e3.x * 32);
        float4 v4 = ld_h4(xc + (size_t)e4.x * 32);
        float4 v5 = ld_h4(xc + (size_t)e5.x * 32);
        float4 v6 = ld_h4(xc + (size_t)e6.x * 32);
        float4 v7 = ld_h4(xc + (size_t)e7.x * 32);
        float w0 = __int_as_float(e0.y), w1 = __int_as_float(e1.y);
        float w2 = __int_as_float(e2.y), w3 = __int_as_float(e3.y);
        float w4 = __int_as_float(e4.y), w5 = __int_as_float(e5.y);
        float w6 = __int_as_float(e6.y), w7 = __int_as_float(e7.y);
        acc.x += w0 * v0.x + w1 * v1.x + w2 * v2.x + w3 * v3.x
               + w4 * v4.x + w5 * v5.x + w6 * v6.x + w7 * v7.x;
        acc.y += w0 * v0.y + w1 * v1.y + w2 * v2.y + w3 * v3.y
               + w4 * v4.y + w5 * v5.y + w6 * v6.y + w7 * v7.y;
        acc.z += w0 * v0.z + w1 * v1.z + w2 * v2.z + w3 * v3.z
               + w4 * v4.z + w5 * v5.z + w6 * v6.z + w7 * v7.z;
        acc.w += w0 * v0.w + w1 * v1.w + w2 * v2.w + w3 * v3.w
               + w4 * v4.w + w5 * v5.w + w6 * v6.w + w7 * v7.w;
    }
    for (; j + 4 <= end; j += 4) {
        int2 e0 = csr[j + 0], e1 = csr[j + 1], e2 = csr[j + 2], e3 = csr[j + 3];
        float4 v0 = ld_h4(xc + (size_t)e0.x * 32);
        float4 v1 = ld_h4(xc + (size_t)e1.x * 32);
        float4 v2 = ld_h4(xc + (size_t)e2.x * 32);
        float4 v3 = ld_h4(xc + (size_t)e3.x * 32);
        float w0 = __int_as_float(e0.y), w1 = __int_as_float(e1.y);
        float w2 = __int_as_float(e2.y), w3 = __int_as_float(e3.y);
        acc.x += w0 * v0.x + w1 * v1.x + w2 * v2.x + w3 * v3.x;
        acc.y += w0 * v0.y + w1 * v1.y + w2 * v2.y + w3 * v3.y;
        acc.z += w0 * v0.z + w1 * v1.z + w2 * v2.z + w3 * v3.z;
        acc.w += w0 * v0.w + w1 * v1.w + w2 * v2.w + w3 * v3.w;
    }
    for (; j < end; j++) {
        int2 e = csr[j];
        float w = __int_as_float(e.y);
        float4 v = ld_h4(xc + (size_t)e.x * 32);
        acc.x += w * v.x; acc.y += w * v.y; acc.z += w * v.z; acc.w += w * v.w;
    }
    st_h4(y + (size_t)n * 32 + c * 4, acc);
}

// ---------------- fused Cheb combine (fp16 I/O, fp32 math) ----------------

__global__ void k_cheb(const __half* T0, const __half* P1, const __half* P2,
                       const __half* res, __half* out,
                       const float* __restrict__ W, const float* __restrict__ b,
                       int do_relu, int has_res) {
    __shared__ float sT0[8][32], sP1[8][32], sP2[8][32], sR[8][32];
    int t = threadIdx.x;
    int nl = t >> 5, o = t & 31;
    int gi = blockIdx.x * 256 + t;
    sT0[nl][o] = __half2float(T0[gi]);
    sP1[nl][o] = __half2float(P1[gi]);
    sP2[nl][o] = __half2float(P2[gi]);
    sR[nl][o] = has_res ? __half2float(res[gi]) : 0.f;
    __syncthreads();
    float acc = b[o] + sR[nl][o];
#pragma unroll
    for (int i = 0; i < 32; i++) {
        float w0 = W[i * 32 + o];
        float w1 = W[1024 + i * 32 + o];
        float w2 = W[2048 + i * 32 + o];
        float t0 = sT0[nl][i];
        acc += t0 * w0 + sP1[nl][i] * w1 + (2.f * sP2[nl][i] - t0) * w2;
    }
    if (do_relu) acc = fmaxf(acc, 0.f);
    out[gi] = __float2half(acc);
}

// ---------------- final head: out = X @ W1 + b1 (fp16 in, fp32 out) ---------

__global__ void k_final(const __half* __restrict__ X, const float* __restrict__ W1,
                        const float* __restrict__ b1, float* __restrict__ out) {
    int n = blockIdx.x * 256 + threadIdx.x;
    if (n < NN) {
        float acc = b1[0];
        const __half* xp = X + (size_t)n * 32;
#pragma unroll
        for (int c = 0; c < 8; c++) {
            float4 v = ld_h4(xp + c * 4);
            acc += v.x * W1[c * 4 + 0] + v.y * W1[c * 4 + 1] +
                   v.z * W1[c * 4 + 2] + v.w * W1[c * 4 + 3];
        }
        out[n] = acc;
    }
}

extern "C" void kernel_launch(void* const* d_in, const int* in_sizes, int n_in,
                              void* d_out, int out_size, void* d_ws, size_t ws_size,
                              hipStream_t stream) {
    const float* x    = (const float*)d_in[0];
    const int*   ei   = (const int*)d_in[1];
    const float* W0   = (const float*)d_in[2];
    const float* b0   = (const float*)d_in[3];
    const float* c11W = (const float*)d_in[4];
    const float* c11b = (const float*)d_in[5];
    const float* c12W = (const float*)d_in[6];
    const float* c12b = (const float*)d_in[7];
    const float* c21W = (const float*)d_in[8];
    const float* c21b = (const float*)d_in[9];
    const float* c22W = (const float*)d_in[10];
    const float* c22b = (const float*)d_in[11];
    const float* W1   = (const float*)d_in[12];
    const float* b1   = (const float*)d_in[13];
    float* out = (float*)d_out;

    char* ws = (char*)d_ws;
    int* dsrc = (int*)ws;     ws += (size_t)NN * 4;   // dsrc+bcnt contiguous:
    int* bcnt = (int*)ws;     ws += (size_t)NB * 4;   // one k_zero covers both
    float* dinv = (float*)ws; ws += (size_t)NN * 4;
    int* bstart = (int*)ws;   ws += (size_t)(NB + 1) * 4;
    int* cursor = (int*)ws;   ws += (size_t)NB * 4;
    int* rowptr = (int*)ws;   ws += (size_t)(NN + 1) * 4;
    ws = (char*)(((uintptr_t)ws + 15) & ~(uintptr_t)15);
    int* ebkt = (int*)ws;     ws += (size_t)EE * 4;              // 12.8 MB
    int2* csr = (int2*)ws;    ws += (size_t)EE * 8;              // 25.6 MB
    __half* F0 = (__half*)ws; ws += (size_t)NN * HID * 2;
    __half* F1 = (__half*)ws; ws += (size_t)NN * HID * 2;
    __half* P1 = (__half*)ws; ws += (size_t)NN * HID * 2;
    __half* P2 = (__half*)ws; ws += (size_t)NN * HID * 2;

    // degrees: src via device atomics (for dinv), dst bucket counts via LDS hist
    k_zero<<<(NN + NB + 255) / 256, 256, 0, stream>>>(dsrc, NN + NB);
    k_degb<<<400, 256, 0, stream>>>(ei, dsrc, bcnt);
    k_dinv<<<(NN + 255) / 256, 256, 0, stream>>>(dsrc, dinv);

    // bucket scan -> bstart/cursor; stage A scatter; stage B exact CSR
    k_bscan<<<1, 256, 0, stream>>>(bcnt, bstart, cursor);
    k_scatb<<<EE / 1024, 256, 0, stream>>>(ei, cursor, ebkt);
    k_fillb<<<NB, 256, 0, stream>>>(bstart, ebkt, dinv, rowptr, csr);

    k_mlp0<<<NN * HID / 256, 256, 0, stream>>>(x, W0, b0, F0);

    auto conv = [&](const __half* T0, const __half* res, __half* outb,
                    const float* W, const float* b, int relu, int has_res) {
        k_prop_csr<<<NN * 8 / 256, 256, 0, stream>>>(rowptr, csr, T0, P1);
        k_prop_csr<<<NN * 8 / 256, 256, 0, stream>>>(rowptr, csr, P1, P2);
        k_cheb<<<NN / 8, 256, 0, stream>>>(T0, P1, P2, res, outb, W, b, relu, has_res);
    };

    conv(F0, nullptr, F1, c11W, c11b, 1, 0);   // block1 conv1: relu
    conv(F1, F0,      F0, c12W, c12b, 1, 1);   // block1 conv2: +res, relu
    conv(F0, nullptr, F1, c21W, c21b, 1, 0);   // block2 conv1: relu
    conv(F1, F0,      F0, c22W, c22b, 1, 1);   // block2 conv2: +res, relu

    k_final<<<(NN + 255) / 256, 256, 0, stream>>>(F0, W1, b1, out);
}

// Round 3
// 1166.609 us; speedup vs baseline: 1.4217x; 1.4217x over previous
//
#include <hip/hip_runtime.h>
#include <hip/hip_fp16.h>

#define NN 200000
#define EE 3200000
#define HID 32

// src-degree histogram (round-0 proven path)
#define HB 16384   // bins per group (64 KB LDS)
#define HG 13      // 13*16384 >= NN
#define HBK 25     // edge slices
#define ESL (EE / HBK)

// block-major two-stage dst sort
#define CH 8000    // edges per stage-A block (32 KB private region)
#define NA 400     // EE / CH
#define NBKT 196   // dst>>10 buckets: 196*1024 = 200704 >= NN

// ---------------- fp16 pack helpers (4 halfs <-> float4, 8B memory op) ------

__device__ inline float4 ld_h4(const __half* p) {
    uint2 u = *reinterpret_cast<const uint2*>(p);
    __half2 a = *reinterpret_cast<__half2*>(&u.x);
    __half2 b = *reinterpret_cast<__half2*>(&u.y);
    float2 fa = __half22float2(a), fb = __half22float2(b);
    return make_float4(fa.x, fa.y, fb.x, fb.y);
}

__device__ inline void st_h4(__half* p, float4 v) {
    __half2 a = __floats2half2_rn(v.x, v.y);
    __half2 b = __floats2half2_rn(v.z, v.w);
    uint2 u;
    u.x = *reinterpret_cast<unsigned*>(&a);
    u.y = *reinterpret_cast<unsigned*>(&b);
    *reinterpret_cast<uint2*>(p) = u;
}

// ---------------- src-degree histogram (LDS atomics only) -------------------

__global__ __launch_bounds__(256) void k_hist(const int* __restrict__ vals,
                                              int* __restrict__ partial) {
    __shared__ int h[HB];
    int b = blockIdx.x / HG, g = blockIdx.x % HG;
    int base = g * HB;
    for (int i = threadIdx.x; i < HB; i += 256) h[i] = 0;
    __syncthreads();
    const int4* p4 = reinterpret_cast<const int4*>(vals + (size_t)b * ESL);
    for (int i = threadIdx.x; i < ESL / 4; i += 256) {
        int4 v = p4[i];
        int a0 = v.x - base, a1 = v.y - base, a2 = v.z - base, a3 = v.w - base;
        if ((unsigned)a0 < HB) atomicAdd(&h[a0], 1);
        if ((unsigned)a1 < HB) atomicAdd(&h[a1], 1);
        if ((unsigned)a2 < HB) atomicAdd(&h[a2], 1);
        if ((unsigned)a3 < HB) atomicAdd(&h[a3], 1);
    }
    __syncthreads();
    int* out = partial + ((size_t)g * HBK + b) * HB;
    for (int i = threadIdx.x; i < HB; i += 256) out[i] = h[i];
}

__global__ void k_hreduce(const int* __restrict__ partial, int* __restrict__ out) {
    int bi = blockIdx.x * 256 + threadIdx.x;
    if (bi >= NN) return;
    int g = bi >> 14, i = bi & (HB - 1);
    const int* p = partial + (size_t)g * HBK * HB + i;
    int s = 0;
#pragma unroll
    for (int b = 0; b < HBK; b++) s += p[(size_t)b << 14];
    out[bi] = s;
}

__global__ void k_dinv(const int* __restrict__ dsrc, float* __restrict__ dinv) {
    int i = blockIdx.x * 256 + threadIdx.x;
    if (i < NN) {
        int d = dsrc[i];
        dinv[i] = d > 0 ? rsqrtf((float)d) : 0.f;
    }
}

// ---------------- stage A: block-major coarse bucket sort -------------------
// Each block owns edges [blk*CH, (blk+1)*CH) and writes ONLY to its private
// contiguous region ebkt[blk*CH ..). No device atomics, no cross-block lines.
// Payload: (src << 10) | (dst & 1023); bucket = dst >> 10.
// Local bucket offsets published to fs[k*NA + blk], k = 0..NBKT.

__global__ __launch_bounds__(256) void k_stageA(const int* __restrict__ ei,
                                                int* __restrict__ fs,
                                                int* __restrict__ ebkt) {
    __shared__ int sdst[CH];
    __shared__ int hist[NBKT], excl[NBKT + 1], rank[NBKT];
    int blk = blockIdx.x, tid = threadIdx.x;
    for (int i = tid; i < NBKT; i += 256) { hist[i] = 0; rank[i] = 0; }
    __syncthreads();
    const int* dptr = ei + EE + (size_t)blk * CH;
    for (int i = tid; i < CH; i += 256) {
        int d = dptr[i];
        sdst[i] = d;
        atomicAdd(&hist[d >> 10], 1);
    }
    __syncthreads();
    if (tid == 0) {
        int run = 0;
        for (int k = 0; k < NBKT; k++) { excl[k] = run; run += hist[k]; }
        excl[NBKT] = run;   // == CH
    }
    __syncthreads();
    for (int k = tid; k <= NBKT; k += 256) fs[k * NA + blk] = excl[k];
    const int* sptr = ei + (size_t)blk * CH;
    int base = blk * CH;
    for (int i = tid; i < CH; i += 256) {
        int d = sdst[i];
        int bkt = d >> 10;
        int r = atomicAdd(&rank[bkt], 1);
        ebkt[base + excl[bkt] + r] = (sptr[i] << 10) | (d & 1023);
    }
}

// ---------------- bucket totals + exclusive scan ----------------------------

__global__ void k_btot(const int* __restrict__ fs, int* __restrict__ btot) {
    __shared__ int s[256];
    int b = blockIdx.x, tid = threadIdx.x;
    int sum = 0;
    for (int blk = tid; blk < NA; blk += 256)
        sum += fs[(b + 1) * NA + blk] - fs[b * NA + blk];
    s[tid] = sum;
    __syncthreads();
    for (int off = 128; off > 0; off >>= 1) {
        if (tid < off) s[tid] += s[tid + off];
        __syncthreads();
    }
    if (tid == 0) btot[b] = s[0];
}

__global__ void k_bscan(const int* __restrict__ btot, int* __restrict__ bstart) {
    __shared__ int s[256];
    int tid = threadIdx.x;
    int v = (tid < NBKT) ? btot[tid] : 0;
    s[tid] = v;
    __syncthreads();
    for (int off = 1; off < 256; off <<= 1) {
        int t = (tid >= off) ? s[tid - off] : 0;
        __syncthreads();
        s[tid] += t;
        __syncthreads();
    }
    if (tid < NBKT) bstart[tid] = s[tid] - v;
    if (tid == 0) bstart[NBKT] = EE;
}

// ---------------- stage B: bucket -> exact-dst CSR + rowptr -----------------
// One block per bucket. Reads 400 fragments (wave-per-fragment, coalesced),
// writes a contiguous csr region. All ranking via LDS atomics.

__global__ __launch_bounds__(1024) void k_stageB(const int* __restrict__ fs,
                                                 const int* __restrict__ bstart,
                                                 const int* __restrict__ ebkt,
                                                 const float* __restrict__ dinv,
                                                 int* __restrict__ rowptr,
                                                 int2* __restrict__ csr) {
    __shared__ int ls0[NA], llen[NA];
    __shared__ int deg[1024], excl[1024], rank[1024];
    __shared__ float sdv[1024];
    int b = blockIdx.x, tid = threadIdx.x;
    int beg = bstart[b];
    if (tid < NA) {
        int o0 = fs[b * NA + tid], o1 = fs[(b + 1) * NA + tid];
        ls0[tid] = tid * CH + o0;
        llen[tid] = o1 - o0;
    }
    deg[tid] = 0; rank[tid] = 0;
    int node = (b << 10) + tid;
    sdv[tid] = (node < NN) ? dinv[node] : 0.f;
    __syncthreads();
    int wave = tid >> 6, lane = tid & 63;   // 16 waves
    for (int f = wave; f < NA; f += 16) {
        int base = ls0[f], len = llen[f];
        for (int k = lane; k < len; k += 64)
            atomicAdd(&deg[ebkt[base + k] & 1023], 1);
    }
    __syncthreads();
    // Hillis-Steele inclusive scan over 1024, then make exclusive
    int v = deg[tid];
    excl[tid] = v;
    __syncthreads();
    for (int off = 1; off < 1024; off <<= 1) {
        int t = (tid >= off) ? excl[tid - off] : 0;
        __syncthreads();
        excl[tid] += t;
        __syncthreads();
    }
    int myexcl = excl[tid] - v;
    __syncthreads();
    excl[tid] = myexcl;
    __syncthreads();
    if (node < NN) rowptr[node] = beg + myexcl;
    if (b == 0 && tid == 0) rowptr[NN] = EE;
    for (int f = wave; f < NA; f += 16) {
        int base = ls0[f], len = llen[f];
        for (int k = lane; k < len; k += 64) {
            int e = ebkt[base + k];
            int l = e & 1023, src = e >> 10;
            int r = atomicAdd(&rank[l], 1);
            float w = -dinv[src] * sdv[l];
            csr[beg + excl[l] + r] = make_int2(src, __float_as_int(w));
        }
    }
}

// ---------------- input MLP: h = relu(x @ W0 + b0), fp16 out ----------------

__global__ void k_mlp0(const float* __restrict__ x, const float* __restrict__ W0,
                       const float* __restrict__ b0, __half* __restrict__ out) {
    int t = blockIdx.x * 256 + threadIdx.x;   // t = n*32 + o
    int n = t >> 5, o = t & 31;
    if (n < NN) {
        float acc = b0[o];
#pragma unroll
        for (int i = 0; i < 3; i++) acc += x[n * 3 + i] * W0[i * 32 + o];
        out[t] = __float2half(fmaxf(acc, 0.f));
    }
}

// ---------------- propagation (CSR, gather-only, fp16 features) -------------
// 8 threads/node, 4 halfs (8B) per thread => 1 cache line per edge row.

__global__ __launch_bounds__(256) void k_prop_csr(const int* __restrict__ rowptr,
                                                  const int2* __restrict__ csr,
                                                  const __half* __restrict__ x,
                                                  __half* __restrict__ y) {
    int t = blockIdx.x * 256 + threadIdx.x;
    int n = t >> 3, c = t & 7;
    if (n >= NN) return;
    int beg = rowptr[n], end = rowptr[n + 1];
    float4 acc = make_float4(0.f, 0.f, 0.f, 0.f);
    int j = beg;
    const __half* xc = x + (size_t)c * 4;
    for (; j + 8 <= end; j += 8) {
        int2 e0 = csr[j + 0], e1 = csr[j + 1], e2 = csr[j + 2], e3 = csr[j + 3];
        int2 e4 = csr[j + 4], e5 = csr[j + 5], e6 = csr[j + 6], e7 = csr[j + 7];
        float4 v0 = ld_h4(xc + (size_t)e0.x * 32);
        float4 v1 = ld_h4(xc + (size_t)e1.x * 32);
        float4 v2 = ld_h4(xc + (size_t)e2.x * 32);
        float4 v3 = ld_h4(xc + (size_t)e3.x * 32);
        float4 v4 = ld_h4(xc + (size_t)e4.x * 32);
        float4 v5 = ld_h4(xc + (size_t)e5.x * 32);
        float4 v6 = ld_h4(xc + (size_t)e6.x * 32);
        float4 v7 = ld_h4(xc + (size_t)e7.x * 32);
        float w0 = __int_as_float(e0.y), w1 = __int_as_float(e1.y);
        float w2 = __int_as_float(e2.y), w3 = __int_as_float(e3.y);
        float w4 = __int_as_float(e4.y), w5 = __int_as_float(e5.y);
        float w6 = __int_as_float(e6.y), w7 = __int_as_float(e7.y);
        acc.x += w0 * v0.x + w1 * v1.x + w2 * v2.x + w3 * v3.x
               + w4 * v4.x + w5 * v5.x + w6 * v6.x + w7 * v7.x;
        acc.y += w0 * v0.y + w1 * v1.y + w2 * v2.y + w3 * v3.y
               + w4 * v4.y + w5 * v5.y + w6 * v6.y + w7 * v7.y;
        acc.z += w0 * v0.z + w1 * v1.z + w2 * v2.z + w3 * v3.z
               + w4 * v4.z + w5 * v5.z + w6 * v6.z + w7 * v7.z;
        acc.w += w0 * v0.w + w1 * v1.w + w2 * v2.w + w3 * v3.w
               + w4 * v4.w + w5 * v5.w + w6 * v6.w + w7 * v7.w;
    }
    for (; j + 4 <= end; j += 4) {
        int2 e0 = csr[j + 0], e1 = csr[j + 1], e2 = csr[j + 2], e3 = csr[j + 3];
        float4 v0 = ld_h4(xc + (size_t)e0.x * 32);
        float4 v1 = ld_h4(xc + (size_t)e1.x * 32);
        float4 v2 = ld_h4(xc + (size_t)e2.x * 32);
        float4 v3 = ld_h4(xc + (size_t)e3.x * 32);
        float w0 = __int_as_float(e0.y), w1 = __int_as_float(e1.y);
        float w2 = __int_as_float(e2.y), w3 = __int_as_float(e3.y);
        acc.x += w0 * v0.x + w1 * v1.x + w2 * v2.x + w3 * v3.x;
        acc.y += w0 * v0.y + w1 * v1.y + w2 * v2.y + w3 * v3.y;
        acc.z += w0 * v0.z + w1 * v1.z + w2 * v2.z + w3 * v3.z;
        acc.w += w0 * v0.w + w1 * v1.w + w2 * v2.w + w3 * v3.w;
    }
    for (; j < end; j++) {
        int2 e = csr[j];
        float w = __int_as_float(e.y);
        float4 v = ld_h4(xc + (size_t)e.x * 32);
        acc.x += w * v.x; acc.y += w * v.y; acc.z += w * v.z; acc.w += w * v.w;
    }
    st_h4(y + (size_t)n * 32 + c * 4, acc);
}

// ---------------- fused Cheb combine (fp16 I/O, fp32 math) ----------------

__global__ void k_cheb(const __half* T0, const __half* P1, const __half* P2,
                       const __half* res, __half* out,
                       const float* __restrict__ W, const float* __restrict__ b,
                       int do_relu, int has_res) {
    __shared__ float sT0[8][32], sP1[8][32], sP2[8][32], sR[8][32];
    int t = threadIdx.x;
    int nl = t >> 5, o = t & 31;
    int gi = blockIdx.x * 256 + t;
    sT0[nl][o] = __half2float(T0[gi]);
    sP1[nl][o] = __half2float(P1[gi]);
    sP2[nl][o] = __half2float(P2[gi]);
    sR[nl][o] = has_res ? __half2float(res[gi]) : 0.f;
    __syncthreads();
    float acc = b[o] + sR[nl][o];
#pragma unroll
    for (int i = 0; i < 32; i++) {
        float w0 = W[i * 32 + o];
        float w1 = W[1024 + i * 32 + o];
        float w2 = W[2048 + i * 32 + o];
        float t0 = sT0[nl][i];
        acc += t0 * w0 + sP1[nl][i] * w1 + (2.f * sP2[nl][i] - t0) * w2;
    }
    if (do_relu) acc = fmaxf(acc, 0.f);
    out[gi] = __float2half(acc);
}

// ---------------- final head: out = X @ W1 + b1 (fp16 in, fp32 out) ---------

__global__ void k_final(const __half* __restrict__ X, const float* __restrict__ W1,
                        const float* __restrict__ b1, float* __restrict__ out) {
    int n = blockIdx.x * 256 + threadIdx.x;
    if (n < NN) {
        float acc = b1[0];
        const __half* xp = X + (size_t)n * 32;
#pragma unroll
        for (int c = 0; c < 8; c++) {
            float4 v = ld_h4(xp + c * 4);
            acc += v.x * W1[c * 4 + 0] + v.y * W1[c * 4 + 1] +
                   v.z * W1[c * 4 + 2] + v.w * W1[c * 4 + 3];
        }
        out[n] = acc;
    }
}

extern "C" void kernel_launch(void* const* d_in, const int* in_sizes, int n_in,
                              void* d_out, int out_size, void* d_ws, size_t ws_size,
                              hipStream_t stream) {
    const float* x    = (const float*)d_in[0];
    const int*   ei   = (const int*)d_in[1];
    const float* W0   = (const float*)d_in[2];
    const float* b0   = (const float*)d_in[3];
    const float* c11W = (const float*)d_in[4];
    const float* c11b = (const float*)d_in[5];
    const float* c12W = (const float*)d_in[6];
    const float* c12b = (const float*)d_in[7];
    const float* c21W = (const float*)d_in[8];
    const float* c21b = (const float*)d_in[9];
    const float* c22W = (const float*)d_in[10];
    const float* c22b = (const float*)d_in[11];
    const float* W1   = (const float*)d_in[12];
    const float* b1   = (const float*)d_in[13];
    float* out = (float*)d_out;

    char* ws = (char*)d_ws;
    int* dsrc = (int*)ws;     ws += (size_t)NN * 4;
    float* dinv = (float*)ws; ws += (size_t)NN * 4;
    int* rowptr = (int*)ws;   ws += (size_t)(NN + 1) * 4;
    int* partial = (int*)ws;  ws += (size_t)HG * HBK * HB * 4;   // 21.3 MB
    int* fs = (int*)ws;       ws += (size_t)(NBKT + 1) * NA * 4; // 315 KB
    int* btot = (int*)ws;     ws += (size_t)NBKT * 4;
    int* bstart = (int*)ws;   ws += (size_t)(NBKT + 1) * 4;
    ws = (char*)(((uintptr_t)ws + 15) & ~(uintptr_t)15);
    int* ebkt = (int*)ws;     ws += (size_t)EE * 4;              // 12.8 MB
    int2* csr = (int2*)ws;    ws += (size_t)EE * 8;              // 25.6 MB
    __half* F0 = (__half*)ws; ws += (size_t)NN * HID * 2;
    __half* F1 = (__half*)ws; ws += (size_t)NN * HID * 2;
    __half* P1 = (__half*)ws; ws += (size_t)NN * HID * 2;
    __half* P2 = (__half*)ws; ws += (size_t)NN * HID * 2;

    // src degrees -> dinv (proven LDS-histogram path)
    k_hist<<<HG * HBK, 256, 0, stream>>>(ei, partial);
    k_hreduce<<<(NN + 255) / 256, 256, 0, stream>>>(partial, dsrc);
    k_dinv<<<(NN + 255) / 256, 256, 0, stream>>>(dsrc, dinv);

    // block-major two-stage dst sort -> exact CSR
    k_stageA<<<NA, 256, 0, stream>>>(ei, fs, ebkt);
    k_btot<<<NBKT, 256, 0, stream>>>(fs, btot);
    k_bscan<<<1, 256, 0, stream>>>(btot, bstart);
    k_stageB<<<NBKT, 1024, 0, stream>>>(fs, bstart, ebkt, dinv, rowptr, csr);

    k_mlp0<<<NN * HID / 256, 256, 0, stream>>>(x, W0, b0, F0);

    auto conv = [&](const __half* T0, const __half* res, __half* outb,
                    const float* W, const float* b, int relu, int has_res) {
        k_prop_csr<<<NN * 8 / 256, 256, 0, stream>>>(rowptr, csr, T0, P1);
        k_prop_csr<<<NN * 8 / 256, 256, 0, stream>>>(rowptr, csr, P1, P2);
        k_cheb<<<NN / 8, 256, 0, stream>>>(T0, P1, P2, res, outb, W, b, relu, has_res);
    };

    conv(F0, nullptr, F1, c11W, c11b, 1, 0);   // block1 conv1: relu
    conv(F1, F0,      F0, c12W, c12b, 1, 1);   // block1 conv2: +res, relu
    conv(F0, nullptr, F1, c21W, c21b, 1, 0);   // block2 conv1: relu
    conv(F1, F0,      F0, c22W, c22b, 1, 1);   // block2 conv2: +res, relu

    k_final<<<(NN + 255) / 256, 256, 0, stream>>>(F0, W1, b1, out);
}

// Round 4
// 1093.044 us; speedup vs baseline: 1.5174x; 1.0673x over previous
//
#include <hip/hip_runtime.h>
#include <hip/hip_fp16.h>

#define NN 200000
#define EE 3200000
#define HID 32

// src-degree histogram (round-0 proven path)
#define HB 16384   // bins per group (64 KB LDS)
#define HG 13      // 13*16384 >= NN
#define HBK 25     // edge slices
#define ESL (EE / HBK)

// block-major two-stage dst sort
#define CH 8000    // edges per stage-A block (32 KB private region)
#define NA 400     // EE / CH
#define NBKT 196   // dst>>10 buckets: 196*1024 = 200704 >= NN

// ---------------- fp16 pack helpers ----------------------------------------

__device__ inline float4 ld_h4(const __half* p) {
    uint2 u = *reinterpret_cast<const uint2*>(p);
    __half2 a = *reinterpret_cast<__half2*>(&u.x);
    __half2 b = *reinterpret_cast<__half2*>(&u.y);
    float2 fa = __half22float2(a), fb = __half22float2(b);
    return make_float4(fa.x, fa.y, fb.x, fb.y);
}

__device__ inline void st_h4(__half* p, float4 v) {
    __half2 a = __floats2half2_rn(v.x, v.y);
    __half2 b = __floats2half2_rn(v.z, v.w);
    uint2 u;
    u.x = *reinterpret_cast<unsigned*>(&a);
    u.y = *reinterpret_cast<unsigned*>(&b);
    *reinterpret_cast<uint2*>(p) = u;
}

// 8 halfs (16B load) -> 8 floats
__device__ inline void ld_h8(const __half* p, float* d) {
    uint4 u = *reinterpret_cast<const uint4*>(p);
    __half2 h; float2 f;
    h = *reinterpret_cast<__half2*>(&u.x); f = __half22float2(h); d[0] = f.x; d[1] = f.y;
    h = *reinterpret_cast<__half2*>(&u.y); f = __half22float2(h); d[2] = f.x; d[3] = f.y;
    h = *reinterpret_cast<__half2*>(&u.z); f = __half22float2(h); d[4] = f.x; d[5] = f.y;
    h = *reinterpret_cast<__half2*>(&u.w); f = __half22float2(h); d[6] = f.x; d[7] = f.y;
}

// 8 floats -> 8 halfs (16B store)
__device__ inline void st_h8(__half* p, const float* s) {
    __half2 h0 = __floats2half2_rn(s[0], s[1]);
    __half2 h1 = __floats2half2_rn(s[2], s[3]);
    __half2 h2 = __floats2half2_rn(s[4], s[5]);
    __half2 h3 = __floats2half2_rn(s[6], s[7]);
    uint4 u;
    u.x = *reinterpret_cast<unsigned*>(&h0);
    u.y = *reinterpret_cast<unsigned*>(&h1);
    u.z = *reinterpret_cast<unsigned*>(&h2);
    u.w = *reinterpret_cast<unsigned*>(&h3);
    *reinterpret_cast<uint4*>(p) = u;
}

// ---------------- src-degree histogram (LDS atomics only) -------------------

__global__ __launch_bounds__(256) void k_hist(const int* __restrict__ vals,
                                              int* __restrict__ partial) {
    __shared__ int h[HB];
    int b = blockIdx.x / HG, g = blockIdx.x % HG;
    int base = g * HB;
    for (int i = threadIdx.x; i < HB; i += 256) h[i] = 0;
    __syncthreads();
    const int4* p4 = reinterpret_cast<const int4*>(vals + (size_t)b * ESL);
    for (int i = threadIdx.x; i < ESL / 4; i += 256) {
        int4 v = p4[i];
        int a0 = v.x - base, a1 = v.y - base, a2 = v.z - base, a3 = v.w - base;
        if ((unsigned)a0 < HB) atomicAdd(&h[a0], 1);
        if ((unsigned)a1 < HB) atomicAdd(&h[a1], 1);
        if ((unsigned)a2 < HB) atomicAdd(&h[a2], 1);
        if ((unsigned)a3 < HB) atomicAdd(&h[a3], 1);
    }
    __syncthreads();
    int* out = partial + ((size_t)g * HBK + b) * HB;
    for (int i = threadIdx.x; i < HB; i += 256) out[i] = h[i];
}

__global__ void k_hreduce(const int* __restrict__ partial, int* __restrict__ out) {
    int bi = blockIdx.x * 256 + threadIdx.x;
    if (bi >= NN) return;
    int g = bi >> 14, i = bi & (HB - 1);
    const int* p = partial + (size_t)g * HBK * HB + i;
    int s = 0;
#pragma unroll
    for (int b = 0; b < HBK; b++) s += p[(size_t)b << 14];
    out[bi] = s;
}

__global__ void k_dinv(const int* __restrict__ dsrc, float* __restrict__ dinv) {
    int i = blockIdx.x * 256 + threadIdx.x;
    if (i < NN) {
        int d = dsrc[i];
        dinv[i] = d > 0 ? rsqrtf((float)d) : 0.f;
    }
}

// ---------------- stage A: block-major coarse bucket sort -------------------

__global__ __launch_bounds__(256) void k_stageA(const int* __restrict__ ei,
                                                int* __restrict__ fs,
                                                int* __restrict__ ebkt) {
    __shared__ int sdst[CH];
    __shared__ int hist[NBKT], excl[NBKT + 1], rank[NBKT];
    int blk = blockIdx.x, tid = threadIdx.x;
    for (int i = tid; i < NBKT; i += 256) { hist[i] = 0; rank[i] = 0; }
    __syncthreads();
    const int* dptr = ei + EE + (size_t)blk * CH;
    for (int i = tid; i < CH; i += 256) {
        int d = dptr[i];
        sdst[i] = d;
        atomicAdd(&hist[d >> 10], 1);
    }
    __syncthreads();
    if (tid == 0) {
        int run = 0;
        for (int k = 0; k < NBKT; k++) { excl[k] = run; run += hist[k]; }
        excl[NBKT] = run;   // == CH
    }
    __syncthreads();
    for (int k = tid; k <= NBKT; k += 256) fs[k * NA + blk] = excl[k];
    const int* sptr = ei + (size_t)blk * CH;
    int base = blk * CH;
    for (int i = tid; i < CH; i += 256) {
        int d = sdst[i];
        int bkt = d >> 10;
        int r = atomicAdd(&rank[bkt], 1);
        ebkt[base + excl[bkt] + r] = (sptr[i] << 10) | (d & 1023);
    }
}

// ---------------- bucket totals + exclusive scan ----------------------------

__global__ void k_btot(const int* __restrict__ fs, int* __restrict__ btot) {
    __shared__ int s[256];
    int b = blockIdx.x, tid = threadIdx.x;
    int sum = 0;
    for (int blk = tid; blk < NA; blk += 256)
        sum += fs[(b + 1) * NA + blk] - fs[b * NA + blk];
    s[tid] = sum;
    __syncthreads();
    for (int off = 128; off > 0; off >>= 1) {
        if (tid < off) s[tid] += s[tid + off];
        __syncthreads();
    }
    if (tid == 0) btot[b] = s[0];
}

__global__ void k_bscan(const int* __restrict__ btot, int* __restrict__ bstart) {
    __shared__ int s[256];
    int tid = threadIdx.x;
    int v = (tid < NBKT) ? btot[tid] : 0;
    s[tid] = v;
    __syncthreads();
    for (int off = 1; off < 256; off <<= 1) {
        int t = (tid >= off) ? s[tid - off] : 0;
        __syncthreads();
        s[tid] += t;
        __syncthreads();
    }
    if (tid < NBKT) bstart[tid] = s[tid] - v;
    if (tid == 0) bstart[NBKT] = EE;
}

// ---------------- stage B: bucket -> exact-dst CSR + rowptr -----------------

__global__ __launch_bounds__(1024) void k_stageB(const int* __restrict__ fs,
                                                 const int* __restrict__ bstart,
                                                 const int* __restrict__ ebkt,
                                                 const float* __restrict__ dinv,
                                                 int* __restrict__ rowptr,
                                                 int2* __restrict__ csr) {
    __shared__ int ls0[NA], llen[NA];
    __shared__ int deg[1024], excl[1024], rank[1024];
    __shared__ float sdv[1024];
    int b = blockIdx.x, tid = threadIdx.x;
    int beg = bstart[b];
    if (tid < NA) {
        int o0 = fs[b * NA + tid], o1 = fs[(b + 1) * NA + tid];
        ls0[tid] = tid * CH + o0;
        llen[tid] = o1 - o0;
    }
    deg[tid] = 0; rank[tid] = 0;
    int node = (b << 10) + tid;
    sdv[tid] = (node < NN) ? dinv[node] : 0.f;
    __syncthreads();
    int wave = tid >> 6, lane = tid & 63;   // 16 waves
    for (int f = wave; f < NA; f += 16) {
        int base = ls0[f], len = llen[f];
        for (int k = lane; k < len; k += 64)
            atomicAdd(&deg[ebkt[base + k] & 1023], 1);
    }
    __syncthreads();
    int v = deg[tid];
    excl[tid] = v;
    __syncthreads();
    for (int off = 1; off < 1024; off <<= 1) {
        int t = (tid >= off) ? excl[tid - off] : 0;
        __syncthreads();
        excl[tid] += t;
        __syncthreads();
    }
    int myexcl = excl[tid] - v;
    __syncthreads();
    excl[tid] = myexcl;
    __syncthreads();
    if (node < NN) rowptr[node] = beg + myexcl;
    if (b == 0 && tid == 0) rowptr[NN] = EE;
    for (int f = wave; f < NA; f += 16) {
        int base = ls0[f], len = llen[f];
        for (int k = lane; k < len; k += 64) {
            int e = ebkt[base + k];
            int l = e & 1023, src = e >> 10;
            int r = atomicAdd(&rank[l], 1);
            float w = -dinv[src] * sdv[l];
            csr[beg + excl[l] + r] = make_int2(src, __float_as_int(w));
        }
    }
}

// ---------------- input MLP: h = relu(x @ W0 + b0), fp16 out ----------------

__global__ void k_mlp0(const float* __restrict__ x, const float* __restrict__ W0,
                       const float* __restrict__ b0, __half* __restrict__ out) {
    int t = blockIdx.x * 256 + threadIdx.x;   // t = n*32 + o
    int n = t >> 5, o = t & 31;
    if (n < NN) {
        float acc = b0[o];
#pragma unroll
        for (int i = 0; i < 3; i++) acc += x[n * 3 + i] * W0[i * 32 + o];
        out[t] = __float2half(fmaxf(acc, 0.f));
    }
}

// ---------------- propagation (CSR, gather-only, fp16 features) -------------

__global__ __launch_bounds__(256) void k_prop_csr(const int* __restrict__ rowptr,
                                                  const int2* __restrict__ csr,
                                                  const __half* __restrict__ x,
                                                  __half* __restrict__ y) {
    int t = blockIdx.x * 256 + threadIdx.x;
    int n = t >> 3, c = t & 7;
    if (n >= NN) return;
    int beg = rowptr[n], end = rowptr[n + 1];
    float4 acc = make_float4(0.f, 0.f, 0.f, 0.f);
    int j = beg;
    const __half* xc = x + (size_t)c * 4;
    for (; j + 8 <= end; j += 8) {
        int2 e0 = csr[j + 0], e1 = csr[j + 1], e2 = csr[j + 2], e3 = csr[j + 3];
        int2 e4 = csr[j + 4], e5 = csr[j + 5], e6 = csr[j + 6], e7 = csr[j + 7];
        float4 v0 = ld_h4(xc + (size_t)e0.x * 32);
        float4 v1 = ld_h4(xc + (size_t)e1.x * 32);
        float4 v2 = ld_h4(xc + (size_t)e2.x * 32);
        float4 v3 = ld_h4(xc + (size_t)e3.x * 32);
        float4 v4 = ld_h4(xc + (size_t)e4.x * 32);
        float4 v5 = ld_h4(xc + (size_t)e5.x * 32);
        float4 v6 = ld_h4(xc + (size_t)e6.x * 32);
        float4 v7 = ld_h4(xc + (size_t)e7.x * 32);
        float w0 = __int_as_float(e0.y), w1 = __int_as_float(e1.y);
        float w2 = __int_as_float(e2.y), w3 = __int_as_float(e3.y);
        float w4 = __int_as_float(e4.y), w5 = __int_as_float(e5.y);
        float w6 = __int_as_float(e6.y), w7 = __int_as_float(e7.y);
        acc.x += w0 * v0.x + w1 * v1.x + w2 * v2.x + w3 * v3.x
               + w4 * v4.x + w5 * v5.x + w6 * v6.x + w7 * v7.x;
        acc.y += w0 * v0.y + w1 * v1.y + w2 * v2.y + w3 * v3.y
               + w4 * v4.y + w5 * v5.y + w6 * v6.y + w7 * v7.y;
        acc.z += w0 * v0.z + w1 * v1.z + w2 * v2.z + w3 * v3.z
               + w4 * v4.z + w5 * v5.z + w6 * v6.z + w7 * v7.z;
        acc.w += w0 * v0.w + w1 * v1.w + w2 * v2.w + w3 * v3.w
               + w4 * v4.w + w5 * v5.w + w6 * v6.w + w7 * v7.w;
    }
    for (; j + 4 <= end; j += 4) {
        int2 e0 = csr[j + 0], e1 = csr[j + 1], e2 = csr[j + 2], e3 = csr[j + 3];
        float4 v0 = ld_h4(xc + (size_t)e0.x * 32);
        float4 v1 = ld_h4(xc + (size_t)e1.x * 32);
        float4 v2 = ld_h4(xc + (size_t)e2.x * 32);
        float4 v3 = ld_h4(xc + (size_t)e3.x * 32);
        float w0 = __int_as_float(e0.y), w1 = __int_as_float(e1.y);
        float w2 = __int_as_float(e2.y), w3 = __int_as_float(e3.y);
        acc.x += w0 * v0.x + w1 * v1.x + w2 * v2.x + w3 * v3.x;
        acc.y += w0 * v0.y + w1 * v1.y + w2 * v2.y + w3 * v3.y;
        acc.z += w0 * v0.z + w1 * v1.z + w2 * v2.z + w3 * v3.z;
        acc.w += w0 * v0.w + w1 * v1.w + w2 * v2.w + w3 * v3.w;
    }
    for (; j < end; j++) {
        int2 e = csr[j];
        float w = __int_as_float(e.y);
        float4 v = ld_h4(xc + (size_t)e.x * 32);
        acc.x += w * v.x; acc.y += w * v.y; acc.z += w * v.z; acc.w += w * v.w;
    }
    st_h4(y + (size_t)n * 32 + c * 4, acc);
}

// ---------------- fused Cheb combine: 1 thread = 1 node, regs GEMV ----------
// All W indices are wave-uniform compile-time constants -> s_load (SMEM pipe);
// features live in registers; inner loop is pure v_fmac_f32 with SGPR operand.

__global__ __launch_bounds__(256) void k_cheb(const __half* __restrict__ T0,
                                              const __half* __restrict__ P1,
                                              const __half* __restrict__ P2,
                                              const __half* __restrict__ res,
                                              __half* __restrict__ out,
                                              const float* __restrict__ W,
                                              const float* __restrict__ b,
                                              int do_relu, int has_res) {
    int n = blockIdx.x * 256 + threadIdx.x;
    if (n >= NN) return;
    size_t off = (size_t)n * 32;

    float t0[32], p1[32], t2[32], acc[32];
#pragma unroll
    for (int q = 0; q < 4; q++) {
        ld_h8(T0 + off + q * 8, t0 + q * 8);
        ld_h8(P1 + off + q * 8, p1 + q * 8);
        ld_h8(P2 + off + q * 8, t2 + q * 8);
    }
#pragma unroll
    for (int i = 0; i < 32; i++) t2[i] = 2.f * t2[i] - t0[i];

    if (has_res) {
#pragma unroll
        for (int q = 0; q < 4; q++) ld_h8(res + off + q * 8, acc + q * 8);
#pragma unroll
        for (int o = 0; o < 32; o++) acc[o] += b[o];
    } else {
#pragma unroll
        for (int o = 0; o < 32; o++) acc[o] = b[o];
    }

#pragma unroll
    for (int i = 0; i < 32; i++) {
        float a0 = t0[i], a1 = p1[i], a2 = t2[i];
#pragma unroll
        for (int o = 0; o < 32; o++)
            acc[o] += a0 * W[i * 32 + o] + a1 * W[1024 + i * 32 + o]
                    + a2 * W[2048 + i * 32 + o];
    }

    if (do_relu) {
#pragma unroll
        for (int o = 0; o < 32; o++) acc[o] = fmaxf(acc[o], 0.f);
    }
#pragma unroll
    for (int q = 0; q < 4; q++) st_h8(out + off + q * 8, acc + q * 8);
}

// ---------------- final head: out = X @ W1 + b1 (fp16 in, fp32 out) ---------

__global__ void k_final(const __half* __restrict__ X, const float* __restrict__ W1,
                        const float* __restrict__ b1, float* __restrict__ out) {
    int n = blockIdx.x * 256 + threadIdx.x;
    if (n < NN) {
        float acc = b1[0];
        const __half* xp = X + (size_t)n * 32;
#pragma unroll
        for (int c = 0; c < 8; c++) {
            float4 v = ld_h4(xp + c * 4);
            acc += v.x * W1[c * 4 + 0] + v.y * W1[c * 4 + 1] +
                   v.z * W1[c * 4 + 2] + v.w * W1[c * 4 + 3];
        }
        out[n] = acc;
    }
}

extern "C" void kernel_launch(void* const* d_in, const int* in_sizes, int n_in,
                              void* d_out, int out_size, void* d_ws, size_t ws_size,
                              hipStream_t stream) {
    const float* x    = (const float*)d_in[0];
    const int*   ei   = (const int*)d_in[1];
    const float* W0   = (const float*)d_in[2];
    const float* b0   = (const float*)d_in[3];
    const float* c11W = (const float*)d_in[4];
    const float* c11b = (const float*)d_in[5];
    const float* c12W = (const float*)d_in[6];
    const float* c12b = (const float*)d_in[7];
    const float* c21W = (const float*)d_in[8];
    const float* c21b = (const float*)d_in[9];
    const float* c22W = (const float*)d_in[10];
    const float* c22b = (const float*)d_in[11];
    const float* W1   = (const float*)d_in[12];
    const float* b1   = (const float*)d_in[13];
    float* out = (float*)d_out;

    char* ws = (char*)d_ws;
    int* dsrc = (int*)ws;     ws += (size_t)NN * 4;
    float* dinv = (float*)ws; ws += (size_t)NN * 4;
    int* rowptr = (int*)ws;   ws += (size_t)(NN + 1) * 4;
    int* partial = (int*)ws;  ws += (size_t)HG * HBK * HB * 4;   // 21.3 MB
    int* fs = (int*)ws;       ws += (size_t)(NBKT + 1) * NA * 4; // 315 KB
    int* btot = (int*)ws;     ws += (size_t)NBKT * 4;
    int* bstart = (int*)ws;   ws += (size_t)(NBKT + 1) * 4;
    ws = (char*)(((uintptr_t)ws + 15) & ~(uintptr_t)15);
    int* ebkt = (int*)ws;     ws += (size_t)EE * 4;              // 12.8 MB
    int2* csr = (int2*)ws;    ws += (size_t)EE * 8;              // 25.6 MB
    __half* F0 = (__half*)ws; ws += (size_t)NN * HID * 2;
    __half* F1 = (__half*)ws; ws += (size_t)NN * HID * 2;
    __half* P1 = (__half*)ws; ws += (size_t)NN * HID * 2;
    __half* P2 = (__half*)ws; ws += (size_t)NN * HID * 2;

    // src degrees -> dinv (proven LDS-histogram path)
    k_hist<<<HG * HBK, 256, 0, stream>>>(ei, partial);
    k_hreduce<<<(NN + 255) / 256, 256, 0, stream>>>(partial, dsrc);
    k_dinv<<<(NN + 255) / 256, 256, 0, stream>>>(dsrc, dinv);

    // block-major two-stage dst sort -> exact CSR
    k_stageA<<<NA, 256, 0, stream>>>(ei, fs, ebkt);
    k_btot<<<NBKT, 256, 0, stream>>>(fs, btot);
    k_bscan<<<1, 256, 0, stream>>>(btot, bstart);
    k_stageB<<<NBKT, 1024, 0, stream>>>(fs, bstart, ebkt, dinv, rowptr, csr);

    k_mlp0<<<NN * HID / 256, 256, 0, stream>>>(x, W0, b0, F0);

    auto conv = [&](const __half* T0, const __half* res, __half* outb,
                    const float* W, const float* b, int relu, int has_res) {
        k_prop_csr<<<NN * 8 / 256, 256, 0, stream>>>(rowptr, csr, T0, P1);
        k_prop_csr<<<NN * 8 / 256, 256, 0, stream>>>(rowptr, csr, P1, P2);
        k_cheb<<<(NN + 255) / 256, 256, 0, stream>>>(T0, P1, P2, res, outb, W, b, relu, has_res);
    };

    conv(F0, nullptr, F1, c11W, c11b, 1, 0);   // block1 conv1: relu
    conv(F1, F0,      F0, c12W, c12b, 1, 1);   // block1 conv2: +res, relu
    conv(F0, nullptr, F1, c21W, c21b, 1, 0);   // block2 conv1: relu
    conv(F1, F0,      F0, c22W, c22b, 1, 1);   // block2 conv2: +res, relu

    k_final<<<(NN + 255) / 256, 256, 0, stream>>>(F0, W1, b1, out);
}

// Round 5
// 965.987 us; speedup vs baseline: 1.7169x; 1.1315x over previous
//
#include <hip/hip_runtime.h>
#include <hip/hip_fp16.h>

#define NN 200000
#define EE 3200000
#define HID 32

// src-degree histogram (round-0 proven path)
#define HB 16384   // bins per group (64 KB LDS)
#define HG 13      // 13*16384 >= NN
#define HBK 25     // edge slices
#define ESL (EE / HBK)

// block-major two-stage dst sort
#define CH 8000    // edges per stage-A block (32 KB private region)
#define NA 400     // EE / CH
#define NBKT 196   // dst>>10 buckets: 196*1024 = 200704 >= NN

// cheb combine
#define CBLK 1000          // grid blocks
#define CBATCH 25          // batches per block: 1000*25*8 = 200000 = NN exactly

// ---------------- fp16 pack helpers ----------------------------------------

__device__ inline float4 ld_h4(const __half* p) {
    uint2 u = *reinterpret_cast<const uint2*>(p);
    __half2 a = *reinterpret_cast<__half2*>(&u.x);
    __half2 b = *reinterpret_cast<__half2*>(&u.y);
    float2 fa = __half22float2(a), fb = __half22float2(b);
    return make_float4(fa.x, fa.y, fb.x, fb.y);
}

__device__ inline void st_h4(__half* p, float4 v) {
    __half2 a = __floats2half2_rn(v.x, v.y);
    __half2 b = __floats2half2_rn(v.z, v.w);
    uint2 u;
    u.x = *reinterpret_cast<unsigned*>(&a);
    u.y = *reinterpret_cast<unsigned*>(&b);
    *reinterpret_cast<uint2*>(p) = u;
}

// ---------------- src-degree histogram (LDS atomics only) -------------------

__global__ __launch_bounds__(256) void k_hist(const int* __restrict__ vals,
                                              int* __restrict__ partial) {
    __shared__ int h[HB];
    int b = blockIdx.x / HG, g = blockIdx.x % HG;
    int base = g * HB;
    for (int i = threadIdx.x; i < HB; i += 256) h[i] = 0;
    __syncthreads();
    const int4* p4 = reinterpret_cast<const int4*>(vals + (size_t)b * ESL);
    for (int i = threadIdx.x; i < ESL / 4; i += 256) {
        int4 v = p4[i];
        int a0 = v.x - base, a1 = v.y - base, a2 = v.z - base, a3 = v.w - base;
        if ((unsigned)a0 < HB) atomicAdd(&h[a0], 1);
        if ((unsigned)a1 < HB) atomicAdd(&h[a1], 1);
        if ((unsigned)a2 < HB) atomicAdd(&h[a2], 1);
        if ((unsigned)a3 < HB) atomicAdd(&h[a3], 1);
    }
    __syncthreads();
    int* out = partial + ((size_t)g * HBK + b) * HB;
    for (int i = threadIdx.x; i < HB; i += 256) out[i] = h[i];
}

__global__ void k_hreduce(const int* __restrict__ partial, int* __restrict__ out) {
    int bi = blockIdx.x * 256 + threadIdx.x;
    if (bi >= NN) return;
    int g = bi >> 14, i = bi & (HB - 1);
    const int* p = partial + (size_t)g * HBK * HB + i;
    int s = 0;
#pragma unroll
    for (int b = 0; b < HBK; b++) s += p[(size_t)b << 14];
    out[bi] = s;
}

__global__ void k_dinv(const int* __restrict__ dsrc, float* __restrict__ dinv) {
    int i = blockIdx.x * 256 + threadIdx.x;
    if (i < NN) {
        int d = dsrc[i];
        dinv[i] = d > 0 ? rsqrtf((float)d) : 0.f;
    }
}

// ---------------- stage A: block-major coarse bucket sort -------------------

__global__ __launch_bounds__(256) void k_stageA(const int* __restrict__ ei,
                                                int* __restrict__ fs,
                                                int* __restrict__ ebkt) {
    __shared__ int sdst[CH];
    __shared__ int hist[NBKT], excl[NBKT + 1], rank[NBKT];
    int blk = blockIdx.x, tid = threadIdx.x;
    for (int i = tid; i < NBKT; i += 256) { hist[i] = 0; rank[i] = 0; }
    __syncthreads();
    const int* dptr = ei + EE + (size_t)blk * CH;
    for (int i = tid; i < CH; i += 256) {
        int d = dptr[i];
        sdst[i] = d;
        atomicAdd(&hist[d >> 10], 1);
    }
    __syncthreads();
    if (tid == 0) {
        int run = 0;
        for (int k = 0; k < NBKT; k++) { excl[k] = run; run += hist[k]; }
        excl[NBKT] = run;   // == CH
    }
    __syncthreads();
    for (int k = tid; k <= NBKT; k += 256) fs[k * NA + blk] = excl[k];
    const int* sptr = ei + (size_t)blk * CH;
    int base = blk * CH;
    for (int i = tid; i < CH; i += 256) {
        int d = sdst[i];
        int bkt = d >> 10;
        int r = atomicAdd(&rank[bkt], 1);
        ebkt[base + excl[bkt] + r] = (sptr[i] << 10) | (d & 1023);
    }
}

// ---------------- bucket totals + exclusive scan ----------------------------

__global__ void k_btot(const int* __restrict__ fs, int* __restrict__ btot) {
    __shared__ int s[256];
    int b = blockIdx.x, tid = threadIdx.x;
    int sum = 0;
    for (int blk = tid; blk < NA; blk += 256)
        sum += fs[(b + 1) * NA + blk] - fs[b * NA + blk];
    s[tid] = sum;
    __syncthreads();
    for (int off = 128; off > 0; off >>= 1) {
        if (tid < off) s[tid] += s[tid + off];
        __syncthreads();
    }
    if (tid == 0) btot[b] = s[0];
}

__global__ void k_bscan(const int* __restrict__ btot, int* __restrict__ bstart) {
    __shared__ int s[256];
    int tid = threadIdx.x;
    int v = (tid < NBKT) ? btot[tid] : 0;
    s[tid] = v;
    __syncthreads();
    for (int off = 1; off < 256; off <<= 1) {
        int t = (tid >= off) ? s[tid - off] : 0;
        __syncthreads();
        s[tid] += t;
        __syncthreads();
    }
    if (tid < NBKT) bstart[tid] = s[tid] - v;
    if (tid == 0) bstart[NBKT] = EE;
}

// ---------------- stage B: bucket -> exact-dst CSR + rowptr -----------------

__global__ __launch_bounds__(1024) void k_stageB(const int* __restrict__ fs,
                                                 const int* __restrict__ bstart,
                                                 const int* __restrict__ ebkt,
                                                 const float* __restrict__ dinv,
                                                 int* __restrict__ rowptr,
                                                 int2* __restrict__ csr) {
    __shared__ int ls0[NA], llen[NA];
    __shared__ int deg[1024], excl[1024], rank[1024];
    __shared__ float sdv[1024];
    int b = blockIdx.x, tid = threadIdx.x;
    int beg = bstart[b];
    if (tid < NA) {
        int o0 = fs[b * NA + tid], o1 = fs[(b + 1) * NA + tid];
        ls0[tid] = tid * CH + o0;
        llen[tid] = o1 - o0;
    }
    deg[tid] = 0; rank[tid] = 0;
    int node = (b << 10) + tid;
    sdv[tid] = (node < NN) ? dinv[node] : 0.f;
    __syncthreads();
    int wave = tid >> 6, lane = tid & 63;   // 16 waves
    for (int f = wave; f < NA; f += 16) {
        int base = ls0[f], len = llen[f];
        for (int k = lane; k < len; k += 64)
            atomicAdd(&deg[ebkt[base + k] & 1023], 1);
    }
    __syncthreads();
    int v = deg[tid];
    excl[tid] = v;
    __syncthreads();
    for (int off = 1; off < 1024; off <<= 1) {
        int t = (tid >= off) ? excl[tid - off] : 0;
        __syncthreads();
        excl[tid] += t;
        __syncthreads();
    }
    int myexcl = excl[tid] - v;
    __syncthreads();
    excl[tid] = myexcl;
    __syncthreads();
    if (node < NN) rowptr[node] = beg + myexcl;
    if (b == 0 && tid == 0) rowptr[NN] = EE;
    for (int f = wave; f < NA; f += 16) {
        int base = ls0[f], len = llen[f];
        for (int k = lane; k < len; k += 64) {
            int e = ebkt[base + k];
            int l = e & 1023, src = e >> 10;
            int r = atomicAdd(&rank[l], 1);
            float w = -dinv[src] * sdv[l];
            csr[beg + excl[l] + r] = make_int2(src, __float_as_int(w));
        }
    }
}

// ---------------- input MLP: h = relu(x @ W0 + b0), fp16 out ----------------

__global__ void k_mlp0(const float* __restrict__ x, const float* __restrict__ W0,
                       const float* __restrict__ b0, __half* __restrict__ out) {
    int t = blockIdx.x * 256 + threadIdx.x;   // t = n*32 + o
    int n = t >> 5, o = t & 31;
    if (n < NN) {
        float acc = b0[o];
#pragma unroll
        for (int i = 0; i < 3; i++) acc += x[n * 3 + i] * W0[i * 32 + o];
        out[t] = __float2half(fmaxf(acc, 0.f));
    }
}

// ---------------- propagation (CSR, gather-only, fp16 features) -------------

__global__ __launch_bounds__(256) void k_prop_csr(const int* __restrict__ rowptr,
                                                  const int2* __restrict__ csr,
                                                  const __half* __restrict__ x,
                                                  __half* __restrict__ y) {
    int t = blockIdx.x * 256 + threadIdx.x;
    int n = t >> 3, c = t & 7;
    if (n >= NN) return;
    int beg = rowptr[n], end = rowptr[n + 1];
    float4 acc = make_float4(0.f, 0.f, 0.f, 0.f);
    int j = beg;
    const __half* xc = x + (size_t)c * 4;
    for (; j + 8 <= end; j += 8) {
        int2 e0 = csr[j + 0], e1 = csr[j + 1], e2 = csr[j + 2], e3 = csr[j + 3];
        int2 e4 = csr[j + 4], e5 = csr[j + 5], e6 = csr[j + 6], e7 = csr[j + 7];
        float4 v0 = ld_h4(xc + (size_t)e0.x * 32);
        float4 v1 = ld_h4(xc + (size_t)e1.x * 32);
        float4 v2 = ld_h4(xc + (size_t)e2.x * 32);
        float4 v3 = ld_h4(xc + (size_t)e3.x * 32);
        float4 v4 = ld_h4(xc + (size_t)e4.x * 32);
        float4 v5 = ld_h4(xc + (size_t)e5.x * 32);
        float4 v6 = ld_h4(xc + (size_t)e6.x * 32);
        float4 v7 = ld_h4(xc + (size_t)e7.x * 32);
        float w0 = __int_as_float(e0.y), w1 = __int_as_float(e1.y);
        float w2 = __int_as_float(e2.y), w3 = __int_as_float(e3.y);
        float w4 = __int_as_float(e4.y), w5 = __int_as_float(e5.y);
        float w6 = __int_as_float(e6.y), w7 = __int_as_float(e7.y);
        acc.x += w0 * v0.x + w1 * v1.x + w2 * v2.x + w3 * v3.x
               + w4 * v4.x + w5 * v5.x + w6 * v6.x + w7 * v7.x;
        acc.y += w0 * v0.y + w1 * v1.y + w2 * v2.y + w3 * v3.y
               + w4 * v4.y + w5 * v5.y + w6 * v6.y + w7 * v7.y;
        acc.z += w0 * v0.z + w1 * v1.z + w2 * v2.z + w3 * v3.z
               + w4 * v4.z + w5 * v5.z + w6 * v6.z + w7 * v7.z;
        acc.w += w0 * v0.w + w1 * v1.w + w2 * v2.w + w3 * v3.w
               + w4 * v4.w + w5 * v5.w + w6 * v6.w + w7 * v7.w;
    }
    for (; j + 4 <= end; j += 4) {
        int2 e0 = csr[j + 0], e1 = csr[j + 1], e2 = csr[j + 2], e3 = csr[j + 3];
        float4 v0 = ld_h4(xc + (size_t)e0.x * 32);
        float4 v1 = ld_h4(xc + (size_t)e1.x * 32);
        float4 v2 = ld_h4(xc + (size_t)e2.x * 32);
        float4 v3 = ld_h4(xc + (size_t)e3.x * 32);
        float w0 = __int_as_float(e0.y), w1 = __int_as_float(e1.y);
        float w2 = __int_as_float(e2.y), w3 = __int_as_float(e3.y);
        acc.x += w0 * v0.x + w1 * v1.x + w2 * v2.x + w3 * v3.x;
        acc.y += w0 * v0.y + w1 * v1.y + w2 * v2.y + w3 * v3.y;
        acc.z += w0 * v0.z + w1 * v1.z + w2 * v2.z + w3 * v3.z;
        acc.w += w0 * v0.w + w1 * v1.w + w2 * v2.w + w3 * v3.w;
    }
    for (; j < end; j++) {
        int2 e = csr[j];
        float w = __int_as_float(e.y);
        float4 v = ld_h4(xc + (size_t)e.x * 32);
        acc.x += w * v.x; acc.y += w * v.y; acc.z += w * v.z; acc.w += w * v.w;
    }
    st_h4(y + (size_t)n * 32 + c * 4, acc);
}

// ---------------- fused Cheb combine v3 -------------------------------------
// thread = (node-slot ng = t>>5, output o = t&31); W columns in VGPRs
// (loaded once, L1-hit); features staged per-8-node-batch via LDS with
// coalesced global loads. Fold: t0*W0 + p1*W1 + (2p2-t0)*W2
//                             = t0*(W0-W2) + p1*W1 + p2*(2W2).

__global__ __launch_bounds__(256) void k_cheb(const __half* __restrict__ T0,
                                              const __half* __restrict__ P1,
                                              const __half* __restrict__ P2,
                                              const __half* __restrict__ res,
                                              __half* __restrict__ out,
                                              const float* __restrict__ W,
                                              const float* __restrict__ b,
                                              int do_relu, int has_res) {
    __shared__ __align__(16) float A[8][100];   // [node][0..31 T0 |32..63 P1 |64..95 P2], pad->100
    __shared__ float R[8][32];
    int t = threadIdx.x;
    int o = t & 31, ng = t >> 5;
    int a = t >> 6, j = t & 63;                 // staging role: wave a, 8B-chunk j

    float w0p[32], w1c[32], w2p[32];
#pragma unroll
    for (int i = 0; i < 32; i++) {
        float wa = W[i * 32 + o];
        float wb = W[1024 + i * 32 + o];
        float wc = W[2048 + i * 32 + o];
        w0p[i] = wa - wc;
        w1c[i] = wb;
        w2p[i] = 2.f * wc;
    }
    float bias = b[o];

    int nn = (4 * j) >> 5, ii = (4 * j) & 31;   // staging dest within batch
    for (int bt = blockIdx.x * CBATCH; bt < blockIdx.x * CBATCH + CBATCH; bt++) {
        size_t base = (size_t)bt * 256;          // halfs (8 nodes * 32)
        if (a < 3 || has_res) {
            const __half* src = (a == 0) ? T0 : (a == 1) ? P1 : (a == 2) ? P2 : res;
            uint2 u = *(reinterpret_cast<const uint2*>(src + base) + j);
            __half2 h0 = *reinterpret_cast<__half2*>(&u.x);
            __half2 h1 = *reinterpret_cast<__half2*>(&u.y);
            float2 f0 = __half22float2(h0), f1 = __half22float2(h1);
            float* dst = (a < 3) ? &A[nn][a * 32 + ii] : &R[nn][ii];
            dst[0] = f0.x; dst[1] = f0.y; dst[2] = f1.x; dst[3] = f1.y;
        }
        __syncthreads();
        float acc = bias + (has_res ? R[ng][o] : 0.f);
#pragma unroll
        for (int q = 0; q < 8; q++) {
            float4 t0 = *reinterpret_cast<float4*>(&A[ng][q * 4]);
            float4 p1 = *reinterpret_cast<float4*>(&A[ng][32 + q * 4]);
            float4 p2 = *reinterpret_cast<float4*>(&A[ng][64 + q * 4]);
            acc += t0.x * w0p[4*q] + t0.y * w0p[4*q+1] + t0.z * w0p[4*q+2] + t0.w * w0p[4*q+3];
            acc += p1.x * w1c[4*q] + p1.y * w1c[4*q+1] + p1.z * w1c[4*q+2] + p1.w * w1c[4*q+3];
            acc += p2.x * w2p[4*q] + p2.y * w2p[4*q+1] + p2.z * w2p[4*q+2] + p2.w * w2p[4*q+3];
        }
        if (do_relu) acc = fmaxf(acc, 0.f);
        out[base + ng * 32 + o] = __float2half(acc);
        __syncthreads();   // A/R reused next batch
    }
}

// ---------------- final head: out = X @ W1 + b1 (fp16 in, fp32 out) ---------

__global__ void k_final(const __half* __restrict__ X, const float* __restrict__ W1,
                        const float* __restrict__ b1, float* __restrict__ out) {
    int n = blockIdx.x * 256 + threadIdx.x;
    if (n < NN) {
        float acc = b1[0];
        const __half* xp = X + (size_t)n * 32;
#pragma unroll
        for (int c = 0; c < 8; c++) {
            float4 v = ld_h4(xp + c * 4);
            acc += v.x * W1[c * 4 + 0] + v.y * W1[c * 4 + 1] +
                   v.z * W1[c * 4 + 2] + v.w * W1[c * 4 + 3];
        }
        out[n] = acc;
    }
}

extern "C" void kernel_launch(void* const* d_in, const int* in_sizes, int n_in,
                              void* d_out, int out_size, void* d_ws, size_t ws_size,
                              hipStream_t stream) {
    const float* x    = (const float*)d_in[0];
    const int*   ei   = (const int*)d_in[1];
    const float* W0   = (const float*)d_in[2];
    const float* b0   = (const float*)d_in[3];
    const float* c11W = (const float*)d_in[4];
    const float* c11b = (const float*)d_in[5];
    const float* c12W = (const float*)d_in[6];
    const float* c12b = (const float*)d_in[7];
    const float* c21W = (const float*)d_in[8];
    const float* c21b = (const float*)d_in[9];
    const float* c22W = (const float*)d_in[10];
    const float* c22b = (const float*)d_in[11];
    const float* W1   = (const float*)d_in[12];
    const float* b1   = (const float*)d_in[13];
    float* out = (float*)d_out;

    char* ws = (char*)d_ws;
    int* dsrc = (int*)ws;     ws += (size_t)NN * 4;
    float* dinv = (float*)ws; ws += (size_t)NN * 4;
    int* rowptr = (int*)ws;   ws += (size_t)(NN + 1) * 4;
    int* partial = (int*)ws;  ws += (size_t)HG * HBK * HB * 4;   // 21.3 MB
    int* fs = (int*)ws;       ws += (size_t)(NBKT + 1) * NA * 4; // 315 KB
    int* btot = (int*)ws;     ws += (size_t)NBKT * 4;
    int* bstart = (int*)ws;   ws += (size_t)(NBKT + 1) * 4;
    ws = (char*)(((uintptr_t)ws + 15) & ~(uintptr_t)15);
    int* ebkt = (int*)ws;     ws += (size_t)EE * 4;              // 12.8 MB
    int2* csr = (int2*)ws;    ws += (size_t)EE * 8;              // 25.6 MB
    __half* F0 = (__half*)ws; ws += (size_t)NN * HID * 2;
    __half* F1 = (__half*)ws; ws += (size_t)NN * HID * 2;
    __half* P1 = (__half*)ws; ws += (size_t)NN * HID * 2;
    __half* P2 = (__half*)ws; ws += (size_t)NN * HID * 2;

    // src degrees -> dinv (proven LDS-histogram path)
    k_hist<<<HG * HBK, 256, 0, stream>>>(ei, partial);
    k_hreduce<<<(NN + 255) / 256, 256, 0, stream>>>(partial, dsrc);
    k_dinv<<<(NN + 255) / 256, 256, 0, stream>>>(dsrc, dinv);

    // block-major two-stage dst sort -> exact CSR
    k_stageA<<<NA, 256, 0, stream>>>(ei, fs, ebkt);
    k_btot<<<NBKT, 256, 0, stream>>>(fs, btot);
    k_bscan<<<1, 256, 0, stream>>>(btot, bstart);
    k_stageB<<<NBKT, 1024, 0, stream>>>(fs, bstart, ebkt, dinv, rowptr, csr);

    k_mlp0<<<NN * HID / 256, 256, 0, stream>>>(x, W0, b0, F0);

    auto conv = [&](const __half* T0, const __half* res, __half* outb,
                    const float* W, const float* b, int relu, int has_res) {
        k_prop_csr<<<NN * 8 / 256, 256, 0, stream>>>(rowptr, csr, T0, P1);
        k_prop_csr<<<NN * 8 / 256, 256, 0, stream>>>(rowptr, csr, P1, P2);
        k_cheb<<<CBLK, 256, 0, stream>>>(T0, P1, P2, res, outb, W, b, relu, has_res);
    };

    conv(F0, nullptr, F1, c11W, c11b, 1, 0);   // block1 conv1: relu
    conv(F1, F0,      F0, c12W, c12b, 1, 1);   // block1 conv2: +res, relu
    conv(F0, nullptr, F1, c21W, c21b, 1, 0);   // block2 conv1: relu
    conv(F1, F0,      F0, c22W, c22b, 1, 1);   // block2 conv2: +res, relu

    k_final<<<(NN + 255) / 256, 256, 0, stream>>>(F0, W1, b1, out);
}